// Round 1
// baseline (110.351 us; speedup 1.0000x reference)
//
#include <hip/hip_runtime.h>

// topk_mean pooling (k=2), exploiting that patch_ids are SORTED along seq:
// each patch's tokens are a contiguous range [start, end) found by binary
// search. For each (b, p, e): m1 = max over range, m2 = max over values
// strictly < m1 (reference masks ALL copies of the max with -1e9), result:
//   n==0 -> 0 ; n==1 (or k==1) -> m1 ; n>=2 -> 0.5*(m1 + max(m2, -1e9)).

#define NEG_INF (-1.0e9f)

__global__ __launch_bounds__(128) void topk_mean_pool(
    const float* __restrict__ h,
    const int*   __restrict__ pid,
    const int*   __restrict__ d_P,   // max_num_patches (device scalar)
    const int*   __restrict__ d_k,   // k (device scalar)
    float*       __restrict__ out,
    int bs_seq,                      // bs * seq  (= in_sizes[1])
    int E,                           // emb dim
    int pairs)                       // bs * P    (= out_size / E)
{
    const int P   = *d_P;
    const int kk  = *d_k;
    const int bs  = pairs / P;
    const int seq = bs_seq / bs;

    const int pair = blockIdx.x;     // pair = b*P + p
    const int b    = pair / P;
    const int p    = pair - b * P;

    const int* row = pid + (size_t)b * seq;

    __shared__ int s_lo, s_hi;
    if (threadIdx.x < 2) {
        // lower_bound(p) for lane 0, lower_bound(p+1) for lane 1
        const int target = p + (int)threadIdx.x;
        int lo = 0, hi = seq;
        while (lo < hi) {
            const int mid = (lo + hi) >> 1;
            if (row[mid] < target) lo = mid + 1; else hi = mid;
        }
        if (threadIdx.x == 0) s_lo = lo; else s_hi = lo;
    }
    __syncthreads();

    const int start = s_lo;
    const int end   = s_hi;
    const int n     = end - start;

    const int Ed4 = E >> 2;  // E assumed divisible by 4 (512 here)
    const float4* hb   = (const float4*)h + (size_t)b * seq * Ed4;
    float4*       out4 = (float4*)out + (size_t)pair * Ed4;

    for (int c = threadIdx.x; c < Ed4; c += blockDim.x) {
        float4 m1 = make_float4(-INFINITY, -INFINITY, -INFINITY, -INFINITY);
        float4 m2 = m1;
        for (int t = start; t < end; ++t) {
            const float4 v = hb[(size_t)t * Ed4 + c];
            if (v.x > m1.x) { m2.x = m1.x; m1.x = v.x; }
            else if (v.x < m1.x && v.x > m2.x) { m2.x = v.x; }
            if (v.y > m1.y) { m2.y = m1.y; m1.y = v.y; }
            else if (v.y < m1.y && v.y > m2.y) { m2.y = v.y; }
            if (v.z > m1.z) { m2.z = m1.z; m1.z = v.z; }
            else if (v.z < m1.z && v.z > m2.z) { m2.z = v.z; }
            if (v.w > m1.w) { m2.w = m1.w; m1.w = v.w; }
            else if (v.w < m1.w && v.w > m2.w) { m2.w = v.w; }
        }
        float4 r;
        if (n == 0) {
            r = make_float4(0.f, 0.f, 0.f, 0.f);
        } else if (n == 1 || kk == 1) {
            r = m1;
        } else {
            r.x = 0.5f * (m1.x + fmaxf(m2.x, NEG_INF));
            r.y = 0.5f * (m1.y + fmaxf(m2.y, NEG_INF));
            r.z = 0.5f * (m1.z + fmaxf(m2.z, NEG_INF));
            r.w = 0.5f * (m1.w + fmaxf(m2.w, NEG_INF));
        }
        out4[c] = r;
    }
}

extern "C" void kernel_launch(void* const* d_in, const int* in_sizes, int n_in,
                              void* d_out, int out_size, void* d_ws, size_t ws_size,
                              hipStream_t stream) {
    const float* h   = (const float*)d_in[0];
    const int*   pid = (const int*)d_in[1];
    const int*   d_P = (const int*)d_in[2];
    const int*   d_k = (const int*)d_in[3];
    float*       out = (float*)d_out;

    const int h_elems = in_sizes[0];       // bs*seq*E
    const int bs_seq  = in_sizes[1];       // bs*seq
    const int E       = h_elems / bs_seq;  // 512
    const int pairs   = out_size / E;      // bs*P

    dim3 grid(pairs), block(128);
    topk_mean_pool<<<grid, block, 0, stream>>>(h, pid, d_P, d_k, out,
                                               bs_seq, E, pairs);
}

// Round 3
// 109.749 us; speedup vs baseline: 1.0055x; 1.0055x over previous
//
#include <hip/hip_runtime.h>

// topk_mean pooling (k=2). patch_ids are SORTED along seq, so each patch is a
// contiguous token run. Two kernels:
//   A) seg_bounds: one thread per (b,p) does lower_bound(p) on the sorted row,
//      writes to d_ws (L2-hot, latency overlapped across waves).
//   B) topk_mean_pool: one block (128 thr) per (b,p); boundaries come from two
//      uniform scalar loads (no binary search, no __syncthreads); token loop is
//      software-pipelined 2-deep so loads stay in flight.
// P (max_num_patches) is a DEVICE scalar -> kernels derive P/bs/seq on device;
// host only uses pairs (= out_size/E) for grid dims.
// Semantics (faithful to reference): m1 = max over run; m2 = max over values
// STRICTLY below m1 (reference masks ALL copies of the max with -1e9);
//   n==0 -> 0 ; n==1 or k==1 -> m1 ; n>=2 -> 0.5*(m1 + max(m2, -1e9)).

#define NEG_INF (-1.0e9f)

__global__ __launch_bounds__(256) void seg_bounds(
    const int* __restrict__ pid,
    const int* __restrict__ d_P,
    int*       __restrict__ bnd,   // [pairs] lower_bound_b(p)
    int bs_seq, int pairs)
{
    const int P   = *d_P;
    const int bs  = pairs / P;
    const int seq = bs_seq / bs;

    const int pair = blockIdx.x * blockDim.x + threadIdx.x;
    if (pair >= pairs) return;
    const int b = pair / P;
    const int p = pair - b * P;
    const int* row = pid + (size_t)b * seq;
    int lo = 0, hi = seq;
    while (lo < hi) {
        const int mid = (lo + hi) >> 1;
        if (row[mid] < p) lo = mid + 1; else hi = mid;
    }
    bnd[pair] = lo;
}

__global__ __launch_bounds__(128) void topk_mean_pool(
    const float* __restrict__ h,
    const int*   __restrict__ bnd,
    const int*   __restrict__ d_P,
    const int*   __restrict__ d_k,
    float*       __restrict__ out,
    int bs_seq, int pairs, int E)
{
    const int P   = *d_P;
    const int bs  = pairs / P;
    const int seq = bs_seq / bs;
    const int kk  = *d_k;

    const int pair = blockIdx.x;     // pair = b*P + p
    const int b    = pair / P;
    const int p    = pair - b * P;

    // Uniform (blockIdx-only) -> scalar loads.
    const int start = bnd[pair];
    const int end   = (p == P - 1) ? seq : bnd[pair + 1];
    const int n     = end - start;

    const int Ed4 = E >> 2;          // 128 for E=512
    const float4* hb   = (const float4*)h + (size_t)b * seq * Ed4;
    float4*       out4 = (float4*)out + (size_t)pair * Ed4;

    for (int c = threadIdx.x; c < Ed4; c += blockDim.x) {
        float4 r;
        if (n == 0) {
            r = make_float4(0.f, 0.f, 0.f, 0.f);
        } else {
            float4 m1 = make_float4(-INFINITY, -INFINITY, -INFINITY, -INFINITY);
            float4 m2 = m1;
            // 2-deep software pipeline: next row load in flight while the
            // current one is consumed.
            float4 v = hb[(size_t)start * Ed4 + c];
            for (int t = start; t < end; ++t) {
                float4 vn = v;
                const int tn = t + 1;
                if (tn < end) vn = hb[(size_t)tn * Ed4 + c];
                if (v.x > m1.x) { m2.x = m1.x; m1.x = v.x; }
                else if (v.x < m1.x && v.x > m2.x) { m2.x = v.x; }
                if (v.y > m1.y) { m2.y = m1.y; m1.y = v.y; }
                else if (v.y < m1.y && v.y > m2.y) { m2.y = v.y; }
                if (v.z > m1.z) { m2.z = m1.z; m1.z = v.z; }
                else if (v.z < m1.z && v.z > m2.z) { m2.z = v.z; }
                if (v.w > m1.w) { m2.w = m1.w; m1.w = v.w; }
                else if (v.w < m1.w && v.w > m2.w) { m2.w = v.w; }
                v = vn;
            }
            if (n == 1 || kk == 1) {
                r = m1;
            } else {
                r.x = 0.5f * (m1.x + fmaxf(m2.x, NEG_INF));
                r.y = 0.5f * (m1.y + fmaxf(m2.y, NEG_INF));
                r.z = 0.5f * (m1.z + fmaxf(m2.z, NEG_INF));
                r.w = 0.5f * (m1.w + fmaxf(m2.w, NEG_INF));
            }
        }
        out4[c] = r;
    }
}

extern "C" void kernel_launch(void* const* d_in, const int* in_sizes, int n_in,
                              void* d_out, int out_size, void* d_ws, size_t ws_size,
                              hipStream_t stream) {
    const float* h   = (const float*)d_in[0];
    const int*   pid = (const int*)d_in[1];
    const int*   d_P = (const int*)d_in[2];
    const int*   d_k = (const int*)d_in[3];
    float*       out = (float*)d_out;
    int*         bnd = (int*)d_ws;

    const int h_elems = in_sizes[0];       // bs*seq*E
    const int bs_seq  = in_sizes[1];       // bs*seq
    const int E       = h_elems / bs_seq;  // 512
    const int pairs   = out_size / E;      // bs*P

    {
        dim3 grid((pairs + 255) / 256), block(256);
        seg_bounds<<<grid, block, 0, stream>>>(pid, d_P, bnd, bs_seq, pairs);
    }
    {
        dim3 grid(pairs), block(128);
        topk_mean_pool<<<grid, block, 0, stream>>>(h, bnd, d_P, d_k, out,
                                                   bs_seq, pairs, E);
    }
}